// Round 4
// baseline (6339.713 us; speedup 1.0000x reference)
//
#include <hip/hip_runtime.h>
#include <stdint.h>

typedef unsigned short u16;
typedef unsigned int u32;
typedef unsigned long long u64;
typedef __attribute__((ext_vector_type(8))) short short8;
typedef __attribute__((ext_vector_type(4))) float f32x4;

#define T_SEQ 1024
#define HDIM  1024
#define NG    3072
#define RING  64
#define SLOTU 16384          // u32 per time-slot: 64 strips * 16 batch * 8 pairs * 2
#define FSTRIDE 32           // u32 stride between progress words (128 B)

__device__ __forceinline__ u16 f2bf(float f) {
  unsigned u = __float_as_uint(f);
  u += 0x7FFF + ((u >> 16) & 1);
  return (u16)(u >> 16);
}
__device__ __forceinline__ float bf2f(u16 h) {
  return __uint_as_float(((unsigned)h) << 16);
}

// async global->LDS, 16B per lane (GEMM staging only). LDS dest = uniform base + lane*16.
__device__ __forceinline__ void gld16(void* lds, const void* g) {
  __builtin_amdgcn_global_load_lds(
      (const __attribute__((address_space(1))) unsigned*)g,
      (__attribute__((address_space(3))) unsigned*)lds, 16, 0, 0);
}

__device__ __forceinline__ void st_agent_u32(unsigned* p, unsigned v) {
  __hip_atomic_store(p, v, __ATOMIC_RELAXED, __HIP_MEMORY_SCOPE_AGENT);
}
__device__ __forceinline__ unsigned ld_agent_u32(const unsigned* p) {
  return __hip_atomic_load(p, __ATOMIC_RELAXED, __HIP_MEMORY_SCOPE_AGENT);
}

// Tagged-pair protocol: each u64 = {lo: 2 bf16 data, hi: tag = step index}.
// Producer: single relaxed agent-scope 8B store, fire-and-forget (no drain/flag).
// Consumer: relaxed agent-scope 8B loads; tag and data arrive in the SAME atomic
// word, so tag==expected proves data freshness with zero ordering requirements.
// Buffers are tag-cleared each launch; tag 0 + data 0.0 doubles as initial h=0.
__device__ __forceinline__ void load_slot(short8 af[8], const u64* slot64,
                                          int fb64, unsigned exptag) {
  for (;;) {
    unsigned bad = 0;
#pragma unroll
    for (int s = 0; s < 8; ++s) {
      const u64* p = slot64 + fb64 + s * 256;
      u64 w0 = __hip_atomic_load(p + 0, __ATOMIC_RELAXED, __HIP_MEMORY_SCOPE_AGENT);
      u64 w1 = __hip_atomic_load(p + 1, __ATOMIC_RELAXED, __HIP_MEMORY_SCOPE_AGENT);
      u64 w2 = __hip_atomic_load(p + 2, __ATOMIC_RELAXED, __HIP_MEMORY_SCOPE_AGENT);
      u64 w3 = __hip_atomic_load(p + 3, __ATOMIC_RELAXED, __HIP_MEMORY_SCOPE_AGENT);
      bad |= ((unsigned)(w0 >> 32) ^ exptag) | ((unsigned)(w1 >> 32) ^ exptag) |
             ((unsigned)(w2 >> 32) ^ exptag) | ((unsigned)(w3 >> 32) ^ exptag);
      uint4 q; q.x = (unsigned)w0; q.y = (unsigned)w1; q.z = (unsigned)w2; q.w = (unsigned)w3;
      af[s] = *(const short8*)&q;
    }
    if (__ballot(bad == 0) == ~0ull) return;
  }
}

__device__ __forceinline__ void store_pair(unsigned* base32, size_t idx32,
                                           unsigned pk, unsigned tag) {
  u64 w = (u64)pk | ((u64)tag << 32);
  __hip_atomic_store((u64*)base32 + (idx32 >> 1), w,
                     __ATOMIC_RELAXED, __HIP_MEMORY_SCOPE_AGENT);
}

// ---------------- clear: zero tag region (h1 ring + h2 slots + prog) ------------
__global__ void clear_kernel(uint4* __restrict__ p, unsigned n) {
  unsigned i = blockIdx.x * 256 + threadIdx.x;
  if (i < n) { uint4 z; z.x = z.y = z.z = z.w = 0u; p[i] = z; }
}

// ---------------- prep: cast 5 weight tensors fp32->bf16 ------------------------
__global__ void cast5_kernel(const float* __restrict__ s0, const float* __restrict__ s1,
                             const float* __restrict__ s2, const float* __restrict__ s3,
                             const float* __restrict__ s4,
                             u16* __restrict__ d0, u16* __restrict__ d1,
                             u16* __restrict__ d2, u16* __restrict__ d3,
                             u16* __restrict__ d4) {
  int bid = blockIdx.x;
  const float* s; u16* d; size_t base;
  if (bid < 3072)       { s = s0; d = d0; base = (size_t)bid * 1024; }
  else if (bid < 6144)  { s = s1; d = d1; base = (size_t)(bid - 3072) * 1024; }
  else if (bid < 9216)  { s = s2; d = d2; base = (size_t)(bid - 6144) * 1024; }
  else if (bid < 12288) { s = s3; d = d3; base = (size_t)(bid - 9216) * 1024; }
  else                  { s = s4; d = d4; base = (size_t)(bid - 12288) * 1024; }
  size_t i = base + (size_t)threadIdx.x * 4;
  float4 v = *(const float4*)(s + i);
  unsigned lo = (unsigned)f2bf(v.x) | ((unsigned)f2bf(v.y) << 16);
  unsigned hi = (unsigned)f2bf(v.z) | ((unsigned)f2bf(v.w) << 16);
  uint2 o; o.x = lo; o.y = hi;
  *(uint2*)(d + i) = o;
}

// ---------------- embedding gather + cast to bf16 ------------------------------
__global__ void gather_cast_kernel(const int* __restrict__ tokens,
                                   const float* __restrict__ emb,
                                   u16* __restrict__ xbf) {
  int row = blockIdx.x;                 // 0..16383  (= b*T + t)
  int tok = tokens[row];
  const float4* src = (const float4*)(emb + (size_t)tok * HDIM);
  float4 v = src[threadIdx.x];
  unsigned lo = (unsigned)f2bf(v.x) | ((unsigned)f2bf(v.y) << 16);
  unsigned hi = (unsigned)f2bf(v.z) | ((unsigned)f2bf(v.w) << 16);
  uint2 o; o.x = lo; o.y = hi;
  *(uint2*)(xbf + (size_t)row * HDIM + (size_t)threadIdx.x * 4) = o;
}

// ---------------- bf16 MFMA GEMM, C[m,n] = sum_k A[m,k]*Bt[n,k] -----------------
// AMODE 0: A plain bf16 row-major [M][K].
// AMODE 1: A = tagged-pair u32 scan layout h2[t][prod][b][pair{data,tag}];
//          logical row r=b*T+t -> slot t+1, data words only (tags skipped).
template <bool OUT_BF16, int AMODE, bool ADD_BIAS>
__global__ __launch_bounds__(256)
void gemm_bt(const u16* __restrict__ A, const u16* __restrict__ Bt,
             void* __restrict__ Cout, const float* __restrict__ bias,
             int M, int N) {
  const int K = 1024;
  __shared__ __align__(16) unsigned char AsRaw[16384];
  __shared__ u16 Bs[128 * 32];
  const int tid = threadIdx.x;
  const int wave = tid >> 6, lane = tid & 63;
  const int quad = lane >> 4, l16 = lane & 15;
  const int wm = (wave & 1) * 64, wn = (wave >> 1) * 64;
  const int m0 = blockIdx.x * 128, n0 = blockIdx.y * 128;
  const int srow = tid >> 2, scol = (tid & 3) * 8;

  size_t abase0 = 0, abase1 = 0;
  size_t abaseP[4];
  if constexpr (AMODE == 1) {
    int li = tid & 7;
#pragma unroll
    for (int rd = 0; rd < 4; ++rd) {
      int r = m0 + rd * 32 + (tid >> 3);
      int b = r >> 10, tt = r & 1023;
      abaseP[rd] = (size_t)(tt + 1) * SLOTU + (size_t)b * 16 +
                   (size_t)(li >> 2) * 256 + (size_t)(li & 3) * 4;
    }
  } else {
    abase0 = (size_t)(m0 + srow) * K + scol;
    abase1 = (size_t)(m0 + 64 + srow) * K + scol;
  }
  const size_t bbase0 = (size_t)(n0 + srow) * K + scol;
  const size_t bbase1 = (size_t)(n0 + 64 + srow) * K + scol;

  f32x4 acc[4][4] = {};

  for (int kk = 0; kk < K; kk += 32) {
    __syncthreads();
    if constexpr (AMODE == 1) {
      u32* As32 = (u32*)AsRaw;
      const u32* Apk = (const u32*)A;
#pragma unroll
      for (int rd = 0; rd < 4; ++rd)
        gld16(As32 + rd * 1024 + tid * 4, Apk + abaseP[rd] + (size_t)(kk >> 4) * 256);
    } else {
      u16* As = (u16*)AsRaw;
      gld16(&As[srow * 32 + scol],        A + abase0 + kk);
      gld16(&As[(64 + srow) * 32 + scol], A + abase1 + kk);
    }
    gld16(&Bs[srow * 32 + scol],        Bt + bbase0 + kk);
    gld16(&Bs[(64 + srow) * 32 + scol], Bt + bbase1 + kk);
    __syncthreads();
    short8 af[4], bfr[4];
    if constexpr (AMODE == 1) {
      const u32* As32 = (const u32*)AsRaw;
#pragma unroll
      for (int mt = 0; mt < 4; ++mt) {
        const uint4* q = (const uint4*)&As32[(wm + mt * 16 + l16) * 32 +
                                             (quad >> 1) * 16 + (quad & 1) * 8];
        uint4 q0 = q[0], q1 = q[1];
        uint4 d; d.x = q0.x; d.y = q0.z; d.z = q1.x; d.w = q1.z;
        af[mt] = *(const short8*)&d;
      }
    } else {
      const u16* As = (const u16*)AsRaw;
#pragma unroll
      for (int mt = 0; mt < 4; ++mt)
        af[mt] = *(const short8*)&As[(wm + mt * 16 + l16) * 32 + quad * 8];
    }
#pragma unroll
    for (int nt = 0; nt < 4; ++nt)
      bfr[nt] = *(const short8*)&Bs[(wn + nt * 16 + l16) * 32 + quad * 8];
#pragma unroll
    for (int mt = 0; mt < 4; ++mt)
#pragma unroll
      for (int nt = 0; nt < 4; ++nt)
        acc[mt][nt] = __builtin_amdgcn_mfma_f32_16x16x32_bf16(af[mt], bfr[nt], acc[mt][nt], 0, 0, 0);
  }
#pragma unroll
  for (int mt = 0; mt < 4; ++mt) {
#pragma unroll
    for (int nt = 0; nt < 4; ++nt) {
#pragma unroll
      for (int r = 0; r < 4; ++r) {
        int m = m0 + wm + mt * 16 + quad * 4 + r;
        int n = n0 + wn + nt * 16 + l16;
        float v = acc[mt][nt][r];
        if (ADD_BIAS) v += bias[n];
        if (OUT_BF16) ((u16*)Cout)[(size_t)m * N + n] = f2bf(v);
        else          ((float*)Cout)[(size_t)m * N + n] = v;
      }
    }
  }
}

// ---------------- fused 2-layer persistent GRU scan, 128 WGs --------------------
// Tagged-pair handshake (see load_slot): ONE device round trip per step instead of
// drain+flag+poll+load. h1 = 64-slot ring (4 MB, cache-hot) with coarse
// back-pressure from layer-1 progress words; h2 = full 1025 slots (logits GEMM
// reads it after the scan). Layer-1's Wih1 slice lives in LDS (96 KB) to avoid
// register spill; Whh1 slice stays in VGPRs.
// Ring-safety invariant: unverified writes cover gens <= 64 only (gen 64 destroys
// the initial gen-0 slot, provably consumed via layer-0 lockstep). Writing gen
// g > 64 requires verified layer-1 progress >= g-65 (=> its future h1 reads are
// gens >= g-63, so destroying gen g-64 is safe). vfgen=65 here was a deadlock race.
__global__ __launch_bounds__(256, 1)
void fused_scan_kernel(const u16* __restrict__ gx0,
                       unsigned* __restrict__ h1p, unsigned* __restrict__ h2p,
                       const u16* __restrict__ Whh0, const u16* __restrict__ Wih1,
                       const u16* __restrict__ Whh1,
                       const float* __restrict__ bih0, const float* __restrict__ bhh0,
                       const float* __restrict__ bih1, const float* __restrict__ bhh1,
                       unsigned* __restrict__ prog) {
  const int tid = threadIdx.x;
  const int wave = tid >> 6, lane = tid & 63;
  const int quad = lane >> 4, l16 = lane & 15;
  const int eb = tid >> 4, ej = tid & 15;

  __shared__ float part[4][6][256];
  __shared__ float biasS[2][3][16];
  __shared__ u16 wx[4 * 3 * 8 * 4 * 16 * 8];   // 96 KB, layer-1 Wih1 slice

  // fragment base (u64 units) within a slot: subtile s adds s*256 (u64).
  const int fb64 = (((16 * wave + (quad >> 1)) * 256 + l16 * 16 + (quad & 1) * 8) >> 1);

  if (blockIdx.x < 64) {
    // ======================= LAYER 0 =======================
    const int wg = blockIdx.x, j0 = wg * 16;
    short8 wf[3][8];
#pragma unroll
    for (int g = 0; g < 3; ++g)
#pragma unroll
      for (int s = 0; s < 8; ++s)
        wf[g][s] = *(const short8*)&Whh0[(size_t)(g * 1024 + j0 + l16) * 1024 + wave * 256 + s * 32 + quad * 8];
    if (tid < 96) {
      int a = tid / 48, rem = tid % 48, g = rem >> 4, jl = rem & 15;
      biasS[a][g][jl] = (a ? bhh0 : bih0)[g * 1024 + j0 + jl];
    }
    const u16* gxp = gx0 + (size_t)eb * T_SEQ * NG + j0 + ej;
    u16 gxu0 = gxp[0], gxu1 = gxp[1024], gxu2 = gxp[2048];
    float hprev = 0.f;
    unsigned vfgen = 64;   // writes of gens <= vfgen proven safe (ring back-pressure)

    for (int t = 0; t < T_SEQ; ++t) {
      int tn = (t + 1 < T_SEQ) ? t + 1 : t;
      const u16* gpn = gx0 + ((size_t)eb * T_SEQ + tn) * NG + j0 + ej;
      u16 ng0 = gpn[0], ng1 = gpn[1024], ng2 = gpn[2048];

      short8 af[8];
      load_slot(af, (const u64*)h1p + (size_t)(t & (RING - 1)) * (SLOTU / 2), fb64, (unsigned)t);

      f32x4 a0 = {0.f,0.f,0.f,0.f}, a1 = {0.f,0.f,0.f,0.f}, a2 = {0.f,0.f,0.f,0.f};
#pragma unroll
      for (int s = 0; s < 8; ++s) {
        a0 = __builtin_amdgcn_mfma_f32_16x16x32_bf16(af[s], wf[0][s], a0, 0, 0, 0);
        a1 = __builtin_amdgcn_mfma_f32_16x16x32_bf16(af[s], wf[1][s], a1, 0, 0, 0);
        a2 = __builtin_amdgcn_mfma_f32_16x16x32_bf16(af[s], wf[2][s], a2, 0, 0, 0);
      }
#pragma unroll
      for (int r = 0; r < 4; ++r) {
        int o = (quad * 4 + r) * 16 + l16;
        part[wave][0][o] = a0[r]; part[wave][1][o] = a1[r]; part[wave][2][o] = a2[r];
      }
      __syncthreads();
      float ghr = part[0][0][tid] + part[1][0][tid] + part[2][0][tid] + part[3][0][tid] + biasS[1][0][ej];
      float ghz = part[0][1][tid] + part[1][1][tid] + part[2][1][tid] + part[3][1][tid] + biasS[1][1][ej];
      float ghn = part[0][2][tid] + part[1][2][tid] + part[2][2][tid] + part[3][2][tid] + biasS[1][2][ej];
      float xr = bf2f(gxu0) + biasS[0][0][ej] + ghr;
      float xz = bf2f(gxu1) + biasS[0][1][ej] + ghz;
      float xn = bf2f(gxu2) + biasS[0][2][ej];
      float r_ = 1.f / (1.f + __expf(-xr));
      float z_ = 1.f / (1.f + __expf(-xz));
      float pre = fminf(fmaxf(xn + r_ * ghn, -15.f), 15.f);
      float e2 = __expf(2.f * pre);
      float n_ = (e2 - 1.f) / (e2 + 1.f);
      float hn = (1.f - z_) * n_ + z_ * hprev;
      hprev = hn;
      gxu0 = ng0; gxu1 = ng1; gxu2 = ng2;

      // ring back-pressure: before writing gen t+1 (destroys gen t-63), ensure
      // layer-1 progressed far enough. Checked ~every 32 steps; instant in steady state.
      if ((unsigned)(t + 1) > vfgen) {
        unsigned thr = (unsigned)(t - 32);
        for (;;) {
          unsigned v = 0xFFFFFFFFu;
          if (lane < 16) v = ld_agent_u32(prog + (size_t)(16 * wave + lane) * FSTRIDE);
          if (__ballot(v >= thr) == ~0ull) break;
        }
        vfgen = thr + 65;
      }

      unsigned mine = (unsigned)f2bf(hn);
      unsigned other = __shfl_xor(mine, 1);
      if (!(tid & 1))
        store_pair(h1p, (size_t)((t + 1) & (RING - 1)) * SLOTU + wg * 256 + eb * 16 + ej,
                   mine | (other << 16), (unsigned)(t + 1));
      __syncthreads();   // protect part[] reuse
    }
  } else {
    // ======================= LAYER 1 =======================
    const int wg = blockIdx.x - 64, j0 = wg * 16;
    short8 wfH[3][8];
#pragma unroll
    for (int g = 0; g < 3; ++g)
#pragma unroll
      for (int s = 0; s < 8; ++s) {
        size_t row = (size_t)(g * 1024 + j0 + l16) * 1024 + wave * 256 + s * 32 + quad * 8;
        wfH[g][s] = *(const short8*)&Whh1[row];
        // stage Wih1 fragment to LDS (each lane writes+reads its own slot; no barrier needed)
        short8 wv = *(const short8*)&Wih1[row];
        *(short8*)&wx[((((wave * 3 + g) * 8 + s) * 4 + quad) * 16 + l16) * 8] = wv;
      }
    if (tid < 96) {
      int a = tid / 48, rem = tid % 48, g = rem >> 4, jl = rem & 15;
      biasS[a][g][jl] = (a ? bhh1 : bih1)[g * 1024 + j0 + jl];
    }
    float hprev = 0.f;
    short8 af1[8];
    load_slot(af1, (const u64*)h1p + (size_t)1 * (SLOTU / 2), fb64, 1u);  // h1 gen 1

    for (int t = 0; t < T_SEQ; ++t) {
      // x-matvec on preloaded af1 (Wih1 fragments from LDS)
      f32x4 x0 = {0.f,0.f,0.f,0.f}, x1 = {0.f,0.f,0.f,0.f}, x2 = {0.f,0.f,0.f,0.f};
#pragma unroll
      for (int s = 0; s < 8; ++s) {
        short8 w0 = *(const short8*)&wx[((((wave * 3 + 0) * 8 + s) * 4 + quad) * 16 + l16) * 8];
        short8 w1 = *(const short8*)&wx[((((wave * 3 + 1) * 8 + s) * 4 + quad) * 16 + l16) * 8];
        short8 w2 = *(const short8*)&wx[((((wave * 3 + 2) * 8 + s) * 4 + quad) * 16 + l16) * 8];
        x0 = __builtin_amdgcn_mfma_f32_16x16x32_bf16(af1[s], w0, x0, 0, 0, 0);
        x1 = __builtin_amdgcn_mfma_f32_16x16x32_bf16(af1[s], w1, x1, 0, 0, 0);
        x2 = __builtin_amdgcn_mfma_f32_16x16x32_bf16(af1[s], w2, x2, 0, 0, 0);
      }
      // h2[t] handoff (own layer, lockstep)
      short8 af2[8];
      load_slot(af2, (const u64*)h2p + (size_t)t * (SLOTU / 2), fb64, (unsigned)t);
      // prefetch next h1 gen (t+2); layer 0 runs ahead -> usually instant
      if (t + 1 < T_SEQ)
        load_slot(af1, (const u64*)h1p + (size_t)((t + 2) & (RING - 1)) * (SLOTU / 2), fb64,
                  (unsigned)(t + 2));

      f32x4 h0 = {0.f,0.f,0.f,0.f}, h1a = {0.f,0.f,0.f,0.f}, h2a = {0.f,0.f,0.f,0.f};
#pragma unroll
      for (int s = 0; s < 8; ++s) {
        h0  = __builtin_amdgcn_mfma_f32_16x16x32_bf16(af2[s], wfH[0][s], h0, 0, 0, 0);
        h1a = __builtin_amdgcn_mfma_f32_16x16x32_bf16(af2[s], wfH[1][s], h1a, 0, 0, 0);
        h2a = __builtin_amdgcn_mfma_f32_16x16x32_bf16(af2[s], wfH[2][s], h2a, 0, 0, 0);
      }
#pragma unroll
      for (int r = 0; r < 4; ++r) {
        int o = (quad * 4 + r) * 16 + l16;
        part[wave][0][o] = x0[r];  part[wave][1][o] = x1[r];  part[wave][2][o] = x2[r];
        part[wave][3][o] = h0[r];  part[wave][4][o] = h1a[r]; part[wave][5][o] = h2a[r];
      }
      __syncthreads();
      float sxr = part[0][0][tid] + part[1][0][tid] + part[2][0][tid] + part[3][0][tid] + biasS[0][0][ej];
      float sxz = part[0][1][tid] + part[1][1][tid] + part[2][1][tid] + part[3][1][tid] + biasS[0][1][ej];
      float sxn = part[0][2][tid] + part[1][2][tid] + part[2][2][tid] + part[3][2][tid] + biasS[0][2][ej];
      float shr = part[0][3][tid] + part[1][3][tid] + part[2][3][tid] + part[3][3][tid] + biasS[1][0][ej];
      float shz = part[0][4][tid] + part[1][4][tid] + part[2][4][tid] + part[3][4][tid] + biasS[1][1][ej];
      float shn = part[0][5][tid] + part[1][5][tid] + part[2][5][tid] + part[3][5][tid] + biasS[1][2][ej];
      float r_ = 1.f / (1.f + __expf(-(sxr + shr)));
      float z_ = 1.f / (1.f + __expf(-(sxz + shz)));
      float pre = fminf(fmaxf(sxn + r_ * shn, -15.f), 15.f);
      float e2 = __expf(2.f * pre);
      float n_ = (e2 - 1.f) / (e2 + 1.f);
      float hn = (1.f - z_) * n_ + z_ * hprev;
      hprev = hn;

      unsigned mine = (unsigned)f2bf(hn);
      unsigned other = __shfl_xor(mine, 1);
      if (!(tid & 1))
        store_pair(h2p, (size_t)(t + 1) * SLOTU + wg * 256 + eb * 16 + ej,
                   mine | (other << 16), (unsigned)(t + 1));
      __syncthreads();   // protect part[] + ensure all waves' af1 prefetch done
      if (tid == 0)
        st_agent_u32(prog + (size_t)wg * FSTRIDE, (unsigned)(t + 1));
    }
  }
}

// ---------------- log_softmax over axis=1 (T): grid (16 b, 8 cgroups) ----------
__global__ void logsoftmax_kernel(float* __restrict__ out) {
  int b = blockIdx.x, cg = blockIdx.y;
  int ci = threadIdx.x & 15, ts = threadIdx.x >> 4;   // 16 cols x 16 t-strips
  int c = cg * 16 + ci;
  float m = -1e30f, s = 0.f;
  for (int t = ts; t < T_SEQ; t += 16) {
    float v = out[((size_t)b * T_SEQ + t) * 128 + c];
    if (v > m) { s = s * __expf(m - v) + 1.f; m = v; }
    else s += __expf(v - m);
  }
  __shared__ float mS[16][16], sS[16][16];
  mS[ts][ci] = m; sS[ts][ci] = s;
  __syncthreads();
  if (ts == 0) {
    float M = mS[0][ci], S = sS[0][ci];
#pragma unroll
    for (int k = 1; k < 16; ++k) {
      float m2 = mS[k][ci], s2 = sS[k][ci];
      float nm = fmaxf(M, m2);
      S = S * __expf(M - nm) + s2 * __expf(m2 - nm);
      M = nm;
    }
    sS[0][ci] = M + logf(S);
  }
  __syncthreads();
  float lsd = sS[0][ci];
  for (int t = ts; t < T_SEQ; t += 16) {
    size_t i = ((size_t)b * T_SEQ + t) * 128 + c;
    out[i] -= lsd;
  }
}

// --------------------------------------------------------------------------------
extern "C" void kernel_launch(void* const* d_in, const int* in_sizes, int n_in,
                              void* d_out, int out_size, void* d_ws, size_t ws_size,
                              hipStream_t stream) {
  const int*   tokens = (const int*)d_in[0];
  const float* emb  = (const float*)d_in[1];
  const float* Wih0 = (const float*)d_in[2];
  const float* Whh0 = (const float*)d_in[3];
  const float* bih0 = (const float*)d_in[4];
  const float* bhh0 = (const float*)d_in[5];
  const float* Wih1 = (const float*)d_in[6];
  const float* Whh1 = (const float*)d_in[7];
  const float* bih1 = (const float*)d_in[8];
  const float* bhh1 = (const float*)d_in[9];
  const float* Wlin = (const float*)d_in[10];
  const float* blin = (const float*)d_in[11];
  float* out = (float*)d_out;

  uint8_t* ws = (uint8_t*)d_ws;
  size_t off = 0;
  auto alloc = [&](size_t bytes) -> void* {
    void* p = ws + off;
    off += (bytes + 255) & ~(size_t)255;
    return p;
  };
  // contiguous tag-cleared region first: h1 ring + h2 slots + progress
  unsigned* h1p  = (unsigned*)alloc((size_t)RING * SLOTU * 4);          //  4 MB
  unsigned* h2p  = (unsigned*)alloc((size_t)(T_SEQ + 1) * SLOTU * 4);   // 67 MB
  unsigned* prog = (unsigned*)alloc((size_t)64 * FSTRIDE * 4);          //  8 KB
  size_t clearBytes = (size_t)RING * SLOTU * 4 + (size_t)(T_SEQ + 1) * SLOTU * 4 +
                      (size_t)64 * FSTRIDE * 4;
  // xbf aliases the h2p region: consumed by the gx GEMM BEFORE clear_kernel runs.
  u16* xbf   = (u16*)h2p;                                               // 33 MB alias
  u16* gxbuf = (u16*)alloc((size_t)16384 * NG * 2);                     // 100 MB
  u16* wih0b = (u16*)alloc((size_t)NG * HDIM * 2);
  u16* whh0b = (u16*)alloc((size_t)NG * HDIM * 2);
  u16* wih1b = (u16*)alloc((size_t)NG * HDIM * 2);
  u16* whh1b = (u16*)alloc((size_t)NG * HDIM * 2);
  u16* wlinb = (u16*)alloc((size_t)128 * HDIM * 2);

  cast5_kernel<<<dim3(12416), dim3(256), 0, stream>>>(
      Wih0, Whh0, Wih1, Whh1, Wlin, wih0b, whh0b, wih1b, whh1b, wlinb);
  gather_cast_kernel<<<dim3(16384), dim3(256), 0, stream>>>(tokens, emb, xbf);
  // gx0 = x @ W_ih0^T
  gemm_bt<true, 0, false><<<dim3(128, 24), dim3(256), 0, stream>>>(
      xbf, wih0b, gxbuf, nullptr, 16384, NG);
  // tag-clear AFTER xbf is consumed (xbf aliases h2p)
  unsigned n16 = (unsigned)(clearBytes / 16);
  clear_kernel<<<dim3((n16 + 255) / 256), dim3(256), 0, stream>>>((uint4*)h1p, n16);
  // fused 2-layer scan (tagged-pair handshake: 1 RT/step)
  fused_scan_kernel<<<dim3(128), dim3(256), 0, stream>>>(
      gxbuf, h1p, h2p, whh0b, wih1b, whh1b, bih0, bhh0, bih1, bhh1, prog);
  // logits = h2 @ W_lin^T + b_lin -> d_out (fp32); A read from tagged h2 slots
  gemm_bt<false, 1, true><<<dim3(128, 1), dim3(256), 0, stream>>>(
      (const u16*)h2p, wlinb, out, blin, 16384, 128);
  // log_softmax over T, in place
  logsoftmax_kernel<<<dim3(16, 8), dim3(256), 0, stream>>>(out);
}

// Round 5
// 3263.284 us; speedup vs baseline: 1.9427x; 1.9427x over previous
//
#include <hip/hip_runtime.h>
#include <stdint.h>

typedef unsigned short u16;
typedef unsigned int u32;
typedef __attribute__((ext_vector_type(8))) short short8;
typedef __attribute__((ext_vector_type(4))) float f32x4;

#define T_SEQ 1024
#define HDIM  1024
#define NG    3072
#define SLOT  16384          // u16 elements per time-slot: 64 strips * 16 batch * 16 cols
#define FSTRIDE 32           // u32 stride between flags (128 B, own line)

__device__ __forceinline__ u16 f2bf(float f) {
  unsigned u = __float_as_uint(f);
  u += 0x7FFF + ((u >> 16) & 1);
  return (u16)(u >> 16);
}
__device__ __forceinline__ float bf2f(u16 h) {
  return __uint_as_float(((unsigned)h) << 16);
}

// async global->LDS, 16B per lane (GEMM staging only). LDS dest = uniform base + lane*16.
__device__ __forceinline__ void gld16(void* lds, const void* g) {
  __builtin_amdgcn_global_load_lds(
      (const __attribute__((address_space(1))) unsigned*)g,
      (__attribute__((address_space(3))) unsigned*)lds, 16, 0, 0);
}

__device__ __forceinline__ void st_agent_u32(unsigned* p, unsigned v) {
  __hip_atomic_store(p, v, __ATOMIC_RELAXED, __HIP_MEMORY_SCOPE_AGENT);
}
__device__ __forceinline__ unsigned ld_agent_u32(const unsigned* p) {
  return __hip_atomic_load(p, __ATOMIC_RELAXED, __HIP_MEMORY_SCOPE_AGENT);
}

// all 64 lanes poll one wave-flag each (producer wg = 16*wave + lane/4, wave = lane%4):
// flag index (wg*4+wv) = 64*wave + lane. Divergent spin; reconvergence = all done.
__device__ __forceinline__ void poll64(const unsigned* flags, int wave, int lane, unsigned need) {
  const unsigned* f = flags + (size_t)(64 * wave + lane) * FSTRIDE;
  while (ld_agent_u32(f) < need) {}
  asm volatile("" ::: "memory");
}

// ---------------- prep: cast 5 weight tensors fp32->bf16, zero flags ------------
__global__ void cast5_kernel(const float* __restrict__ s0, const float* __restrict__ s1,
                             const float* __restrict__ s2, const float* __restrict__ s3,
                             const float* __restrict__ s4,
                             u16* __restrict__ d0, u16* __restrict__ d1,
                             u16* __restrict__ d2, u16* __restrict__ d3,
                             u16* __restrict__ d4, unsigned* __restrict__ flags) {
  if (blockIdx.x == 0) {
#pragma unroll
    for (int k = 0; k < 64; ++k) flags[threadIdx.x * 64 + k] = 0;  // 64 KB of flags
  }
  int bid = blockIdx.x;
  const float* s; u16* d; size_t base;
  if (bid < 3072)       { s = s0; d = d0; base = (size_t)bid * 1024; }
  else if (bid < 6144)  { s = s1; d = d1; base = (size_t)(bid - 3072) * 1024; }
  else if (bid < 9216)  { s = s2; d = d2; base = (size_t)(bid - 6144) * 1024; }
  else if (bid < 12288) { s = s3; d = d3; base = (size_t)(bid - 9216) * 1024; }
  else                  { s = s4; d = d4; base = (size_t)(bid - 12288) * 1024; }
  size_t i = base + (size_t)threadIdx.x * 4;
  float4 v = *(const float4*)(s + i);
  unsigned lo = (unsigned)f2bf(v.x) | ((unsigned)f2bf(v.y) << 16);
  unsigned hi = (unsigned)f2bf(v.z) | ((unsigned)f2bf(v.w) << 16);
  uint2 o; o.x = lo; o.y = hi;
  *(uint2*)(d + i) = o;
}

// ---------------- embedding gather + cast to bf16 ------------------------------
__global__ void gather_cast_kernel(const int* __restrict__ tokens,
                                   const float* __restrict__ emb,
                                   u16* __restrict__ xbf) {
  int row = blockIdx.x;                 // 0..16383  (= b*T + t)
  int tok = tokens[row];
  const float4* src = (const float4*)(emb + (size_t)tok * HDIM);
  float4 v = src[threadIdx.x];
  unsigned lo = (unsigned)f2bf(v.x) | ((unsigned)f2bf(v.y) << 16);
  unsigned hi = (unsigned)f2bf(v.z) | ((unsigned)f2bf(v.w) << 16);
  uint2 o; o.x = lo; o.y = hi;
  *(uint2*)(xbf + (size_t)row * HDIM + (size_t)threadIdx.x * 4) = o;
}

// ---------------- bf16 MFMA GEMM, C[m,n] = sum_k A[m,k]*Bt[n,k] -----------------
// A_PACKED: A is the packed scan layout h[t][prod][b][16]; logical row r = b*T+t
// maps to slot t+1 (state after step t).
// OUT_MODE 0: fp32 plain [m*N+n].  OUT_MODE 2: bf16 gx-packed gx[t][wg][gate][b][ej].
template <int OUT_MODE, bool A_PACKED, bool ADD_BIAS>
__global__ __launch_bounds__(256)
void gemm_bt(const u16* __restrict__ A, const u16* __restrict__ Bt,
             void* __restrict__ Cout, const float* __restrict__ bias,
             int M, int N) {
  const int K = 1024;
  __shared__ u16 As[128 * 32];
  __shared__ u16 Bs[128 * 32];
  const int tid = threadIdx.x;
  const int wave = tid >> 6, lane = tid & 63;
  const int quad = lane >> 4, l16 = lane & 15;
  const int wm = (wave & 1) * 64, wn = (wave >> 1) * 64;
  const int m0 = blockIdx.x * 128, n0 = blockIdx.y * 128;
  const int srow = tid >> 2, scol = (tid & 3) * 8;

  size_t abase0, abase1;
  {
    int r0 = m0 + srow, r1 = m0 + 64 + srow;
    if (A_PACKED) {
      abase0 = (size_t)((r0 & 1023) + 1) * SLOT + (size_t)(r0 >> 10) * 16 +
               (size_t)(scol & 8) + (size_t)(scol >> 4) * 256;
      abase1 = (size_t)((r1 & 1023) + 1) * SLOT + (size_t)(r1 >> 10) * 16 +
               (size_t)(scol & 8) + (size_t)(scol >> 4) * 256;
    } else {
      abase0 = (size_t)r0 * K + scol;
      abase1 = (size_t)r1 * K + scol;
    }
  }
  const size_t bbase0 = (size_t)(n0 + srow) * K + scol;
  const size_t bbase1 = (size_t)(n0 + 64 + srow) * K + scol;

  f32x4 acc[4][4] = {};

  for (int kk = 0; kk < K; kk += 32) {
    __syncthreads();
    size_t ka = A_PACKED ? (size_t)kk * 16 : (size_t)kk;   // 32 cols = 2 strips = 512 elems
    gld16(&As[srow * 32 + scol],        A + abase0 + ka);
    gld16(&As[(64 + srow) * 32 + scol], A + abase1 + ka);
    gld16(&Bs[srow * 32 + scol],        Bt + bbase0 + kk);
    gld16(&Bs[(64 + srow) * 32 + scol], Bt + bbase1 + kk);
    __syncthreads();
    short8 af[4], bfr[4];
#pragma unroll
    for (int mt = 0; mt < 4; ++mt)
      af[mt] = *(const short8*)&As[(wm + mt * 16 + l16) * 32 + quad * 8];
#pragma unroll
    for (int nt = 0; nt < 4; ++nt)
      bfr[nt] = *(const short8*)&Bs[(wn + nt * 16 + l16) * 32 + quad * 8];
#pragma unroll
    for (int mt = 0; mt < 4; ++mt)
#pragma unroll
      for (int nt = 0; nt < 4; ++nt)
        acc[mt][nt] = __builtin_amdgcn_mfma_f32_16x16x32_bf16(af[mt], bfr[nt], acc[mt][nt], 0, 0, 0);
  }
#pragma unroll
  for (int mt = 0; mt < 4; ++mt) {
#pragma unroll
    for (int nt = 0; nt < 4; ++nt) {
#pragma unroll
      for (int r = 0; r < 4; ++r) {
        int m = m0 + wm + mt * 16 + quad * 4 + r;
        int n = n0 + wn + nt * 16 + l16;
        float v = acc[mt][nt][r];
        if (ADD_BIAS) v += bias[n];
        if (OUT_MODE == 2) {
          int t = m & 1023, b = m >> 10, g = n >> 10, c = n & 1023;
          size_t idx = ((((size_t)t * 64 + (c >> 4)) * 3 + g) * 16 + b) * 16 + (c & 15);
          ((u16*)Cout)[idx] = f2bf(v);
        } else {
          ((float*)Cout)[(size_t)m * N + n] = v;
        }
      }
    }
  }
}

// ---------------- fused 2-layer persistent GRU scan, 128 WGs --------------------
// h layout: h[t][producer wg 0..63][batch 0..15][16 cols] bf16. PER-WAVE flags:
// producer wave stores its 128 B chunk (batches 4w..4w+3), drains with in-wave
// s_waitcnt vmcnt(0), then fires its own flag (relaxed; drain already ordered it).
// Consumer wave polls 64 wave-flags (1/lane). One barrier/step: part[] is
// double-buffered (pb = t&1), the write->reduce barrier also gives cross-step
// protection. gx is packed per-(t,wg): 3x512B contiguous reads per WG per step.
__global__ __launch_bounds__(256, 1)
void fused_scan_kernel(const u16* __restrict__ gx0,
                       u16* __restrict__ h1seq, u16* __restrict__ h2seq,
                       const u16* __restrict__ Whh0, const u16* __restrict__ Wih1,
                       const u16* __restrict__ Whh1,
                       const float* __restrict__ bih0, const float* __restrict__ bhh0,
                       const float* __restrict__ bih1, const float* __restrict__ bhh1,
                       unsigned* __restrict__ flags0, unsigned* __restrict__ flags1) {
  const int tid = threadIdx.x;
  const int wave = tid >> 6, lane = tid & 63;
  const int quad = lane >> 4, l16 = lane & 15;
  const int eb = tid >> 4, ej = tid & 15;

  __shared__ float part[2][4][6][256];         // 48 KB, double-buffered
  __shared__ float biasS[2][3][16];
  __shared__ u16 wx[4 * 3 * 8 * 4 * 16 * 8];   // 96 KB, layer-1 Wih1 slice

  // fragment source offset within a slot: prod = 16w + 2s + (quad>>1),
  // elem = prod*256 + batch(l16)*16 + (quad&1)*8 ; + s*512 per k-subtile
  const int fragoff = (16 * wave + (quad >> 1)) * 256 + l16 * 16 + (quad & 1) * 8;

  if (blockIdx.x < 64) {
    // ======================= LAYER 0 =======================
    const int wg = blockIdx.x, j0 = wg * 16;
    short8 wf[3][8];
#pragma unroll
    for (int g = 0; g < 3; ++g)
#pragma unroll
      for (int s = 0; s < 8; ++s)
        wf[g][s] = *(const short8*)&Whh0[(size_t)(g * 1024 + j0 + l16) * 1024 + wave * 256 + s * 32 + quad * 8];
    if (tid < 96) {
      int a = tid / 48, rem = tid % 48, g = rem >> 4, jl = rem & 15;
      biasS[a][g][jl] = (a ? bhh0 : bih0)[g * 1024 + j0 + jl];
    }
    // zero own 128B chunk of slot 0, drain, per-wave flag = 1
    if (lane < 32) st_agent_u32((unsigned*)h1seq + wg * 128 + wave * 32 + lane, 0u);
    asm volatile("s_waitcnt vmcnt(0)" ::: "memory");
    if (lane == 0) st_agent_u32(flags0 + (size_t)(wg * 4 + wave) * FSTRIDE, 1u);

    const u16* gxp = gx0 + (size_t)(wg * 3) * 256 + eb * 16 + ej;   // t = 0
    u16 gxu0 = gxp[0], gxu1 = gxp[256], gxu2 = gxp[512];
    float hprev = 0.f;

    for (int t = 0; t < T_SEQ; ++t) {
      const int pb = t & 1;
      poll64(flags0, wave, lane, (unsigned)(t + 1));
      const u16* src = h1seq + (size_t)t * SLOT + fragoff;
      short8 af[8];
#pragma unroll
      for (int s = 0; s < 8; ++s) af[s] = *(const short8*)(src + s * 512);
      f32x4 a0 = {0.f,0.f,0.f,0.f}, a1 = {0.f,0.f,0.f,0.f}, a2 = {0.f,0.f,0.f,0.f};
#pragma unroll
      for (int s = 0; s < 8; ++s) {
        a0 = __builtin_amdgcn_mfma_f32_16x16x32_bf16(af[s], wf[0][s], a0, 0, 0, 0);
        a1 = __builtin_amdgcn_mfma_f32_16x16x32_bf16(af[s], wf[1][s], a1, 0, 0, 0);
        a2 = __builtin_amdgcn_mfma_f32_16x16x32_bf16(af[s], wf[2][s], a2, 0, 0, 0);
      }
#pragma unroll
      for (int r = 0; r < 4; ++r) {
        int o = (quad * 4 + r) * 16 + l16;
        part[pb][wave][0][o] = a0[r]; part[pb][wave][1][o] = a1[r]; part[pb][wave][2][o] = a2[r];
      }
      __syncthreads();   // the ONE barrier per step
      float ghr = part[pb][0][0][tid] + part[pb][1][0][tid] + part[pb][2][0][tid] + part[pb][3][0][tid] + biasS[1][0][ej];
      float ghz = part[pb][0][1][tid] + part[pb][1][1][tid] + part[pb][2][1][tid] + part[pb][3][1][tid] + biasS[1][1][ej];
      float ghn = part[pb][0][2][tid] + part[pb][1][2][tid] + part[pb][2][2][tid] + part[pb][3][2][tid] + biasS[1][2][ej];
      float xr = bf2f(gxu0) + biasS[0][0][ej] + ghr;
      float xz = bf2f(gxu1) + biasS[0][1][ej] + ghz;
      float xn = bf2f(gxu2) + biasS[0][2][ej];
      float r_ = 1.f / (1.f + __expf(-xr));
      float z_ = 1.f / (1.f + __expf(-xz));
      float pre = fminf(fmaxf(xn + r_ * ghn, -15.f), 15.f);
      float e2 = __expf(2.f * pre);
      float n_ = (e2 - 1.f) / (e2 + 1.f);
      float hn = (1.f - z_) * n_ + z_ * hprev;
      hprev = hn;

      unsigned mine = (unsigned)f2bf(hn);
      unsigned other = __shfl_xor(mine, 1);
      if (!(tid & 1))
        st_agent_u32((unsigned*)h1seq + (size_t)(t + 1) * (SLOT / 2) + wg * 128 + (tid >> 1),
                     mine | (other << 16));
      asm volatile("s_waitcnt vmcnt(0)" ::: "memory");   // per-wave drain of h stores
      if (lane == 0)
        st_agent_u32(flags0 + (size_t)(wg * 4 + wave) * FSTRIDE, (unsigned)(t + 2));
      // prefetch next step's packed gx (issued after drain so it never blocks it)
      int tn = (t + 1 < T_SEQ) ? t + 1 : t;
      const u16* gpn = gx0 + (size_t)(tn * 64 + wg) * 3 * 256 + eb * 16 + ej;
      gxu0 = gpn[0]; gxu1 = gpn[256]; gxu2 = gpn[512];
    }
  } else {
    // ======================= LAYER 1 =======================
    const int wg = blockIdx.x - 64, j0 = wg * 16;
    short8 wfH[3][8];
#pragma unroll
    for (int g = 0; g < 3; ++g)
#pragma unroll
      for (int s = 0; s < 8; ++s) {
        size_t row = (size_t)(g * 1024 + j0 + l16) * 1024 + wave * 256 + s * 32 + quad * 8;
        wfH[g][s] = *(const short8*)&Whh1[row];
        // stage Wih1 fragment to LDS (each lane writes+reads its own slot; no barrier needed)
        short8 wv = *(const short8*)&Wih1[row];
        *(short8*)&wx[((((wave * 3 + g) * 8 + s) * 4 + quad) * 16 + l16) * 8] = wv;
      }
    if (tid < 96) {
      int a = tid / 48, rem = tid % 48, g = rem >> 4, jl = rem & 15;
      biasS[a][g][jl] = (a ? bhh1 : bih1)[g * 1024 + j0 + jl];
    }
    if (lane < 32) st_agent_u32((unsigned*)h2seq + wg * 128 + wave * 32 + lane, 0u);
    asm volatile("s_waitcnt vmcnt(0)" ::: "memory");
    if (lane == 0) st_agent_u32(flags1 + (size_t)(wg * 4 + wave) * FSTRIDE, 1u);

    float hprev = 0.f;
    short8 af1[8];
    poll64(flags0, wave, lane, 2u);            // h1 gen 1 ready
    {
      const u16* s1 = h1seq + (size_t)SLOT + fragoff;
#pragma unroll
      for (int s = 0; s < 8; ++s) af1[s] = *(const short8*)(s1 + s * 512);
    }

    for (int t = 0; t < T_SEQ; ++t) {
      const int pb = t & 1;
      // x-matvec on preloaded af1 (Wih1 fragments from LDS)
      f32x4 x0 = {0.f,0.f,0.f,0.f}, x1 = {0.f,0.f,0.f,0.f}, x2 = {0.f,0.f,0.f,0.f};
#pragma unroll
      for (int s = 0; s < 8; ++s) {
        short8 w0 = *(const short8*)&wx[((((wave * 3 + 0) * 8 + s) * 4 + quad) * 16 + l16) * 8];
        short8 w1 = *(const short8*)&wx[((((wave * 3 + 1) * 8 + s) * 4 + quad) * 16 + l16) * 8];
        short8 w2 = *(const short8*)&wx[((((wave * 3 + 2) * 8 + s) * 4 + quad) * 16 + l16) * 8];
        x0 = __builtin_amdgcn_mfma_f32_16x16x32_bf16(af1[s], w0, x0, 0, 0, 0);
        x1 = __builtin_amdgcn_mfma_f32_16x16x32_bf16(af1[s], w1, x1, 0, 0, 0);
        x2 = __builtin_amdgcn_mfma_f32_16x16x32_bf16(af1[s], w2, x2, 0, 0, 0);
      }
      // h2[t] handoff (own layer, lockstep)
      poll64(flags1, wave, lane, (unsigned)(t + 1));
      short8 af2[8];
      const u16* s2 = h2seq + (size_t)t * SLOT + fragoff;
#pragma unroll
      for (int s = 0; s < 8; ++s) af2[s] = *(const short8*)(s2 + s * 512);
      // prefetch next h1 gen (slot t+2); layer 0 runs ahead -> usually instant
      if (t + 1 < T_SEQ) {
        poll64(flags0, wave, lane, (unsigned)(t + 3));
        const u16* s1 = h1seq + (size_t)(t + 2) * SLOT + fragoff;
#pragma unroll
        for (int s = 0; s < 8; ++s) af1[s] = *(const short8*)(s1 + s * 512);
      }
      f32x4 h0 = {0.f,0.f,0.f,0.f}, h1a = {0.f,0.f,0.f,0.f}, h2a = {0.f,0.f,0.f,0.f};
#pragma unroll
      for (int s = 0; s < 8; ++s) {
        h0  = __builtin_amdgcn_mfma_f32_16x16x32_bf16(af2[s], wfH[0][s], h0, 0, 0, 0);
        h1a = __builtin_amdgcn_mfma_f32_16x16x32_bf16(af2[s], wfH[1][s], h1a, 0, 0, 0);
        h2a = __builtin_amdgcn_mfma_f32_16x16x32_bf16(af2[s], wfH[2][s], h2a, 0, 0, 0);
      }
#pragma unroll
      for (int r = 0; r < 4; ++r) {
        int o = (quad * 4 + r) * 16 + l16;
        part[pb][wave][0][o] = x0[r];  part[pb][wave][1][o] = x1[r];  part[pb][wave][2][o] = x2[r];
        part[pb][wave][3][o] = h0[r];  part[pb][wave][4][o] = h1a[r]; part[pb][wave][5][o] = h2a[r];
      }
      __syncthreads();
      float sxr = part[pb][0][0][tid] + part[pb][1][0][tid] + part[pb][2][0][tid] + part[pb][3][0][tid] + biasS[0][0][ej];
      float sxz = part[pb][0][1][tid] + part[pb][1][1][tid] + part[pb][2][1][tid] + part[pb][3][1][tid] + biasS[0][1][ej];
      float sxn = part[pb][0][2][tid] + part[pb][1][2][tid] + part[pb][2][2][tid] + part[pb][3][2][tid] + biasS[0][2][ej];
      float shr = part[pb][0][3][tid] + part[pb][1][3][tid] + part[pb][2][3][tid] + part[pb][3][3][tid] + biasS[1][0][ej];
      float shz = part[pb][0][4][tid] + part[pb][1][4][tid] + part[pb][2][4][tid] + part[pb][3][4][tid] + biasS[1][1][ej];
      float shn = part[pb][0][5][tid] + part[pb][1][5][tid] + part[pb][2][5][tid] + part[pb][3][5][tid] + biasS[1][2][ej];
      float r_ = 1.f / (1.f + __expf(-(sxr + shr)));
      float z_ = 1.f / (1.f + __expf(-(sxz + shz)));
      float pre = fminf(fmaxf(sxn + r_ * shn, -15.f), 15.f);
      float e2 = __expf(2.f * pre);
      float n_ = (e2 - 1.f) / (e2 + 1.f);
      float hn = (1.f - z_) * n_ + z_ * hprev;
      hprev = hn;

      unsigned mine = (unsigned)f2bf(hn);
      unsigned other = __shfl_xor(mine, 1);
      if (!(tid & 1))
        st_agent_u32((unsigned*)h2seq + (size_t)(t + 1) * (SLOT / 2) + wg * 128 + (tid >> 1),
                     mine | (other << 16));
      asm volatile("s_waitcnt vmcnt(0)" ::: "memory");   // drains h2 stores (+ af1 prefetch)
      if (lane == 0)
        st_agent_u32(flags1 + (size_t)(wg * 4 + wave) * FSTRIDE, (unsigned)(t + 2));
    }
  }
}

// ---------------- log_softmax over axis=1 (T): grid (16 b, 8 cgroups) ----------
__global__ void logsoftmax_kernel(float* __restrict__ out) {
  int b = blockIdx.x, cg = blockIdx.y;
  int ci = threadIdx.x & 15, ts = threadIdx.x >> 4;   // 16 cols x 16 t-strips
  int c = cg * 16 + ci;
  float m = -1e30f, s = 0.f;
  for (int t = ts; t < T_SEQ; t += 16) {
    float v = out[((size_t)b * T_SEQ + t) * 128 + c];
    if (v > m) { s = s * __expf(m - v) + 1.f; m = v; }
    else s += __expf(v - m);
  }
  __shared__ float mS[16][16], sS[16][16];
  mS[ts][ci] = m; sS[ts][ci] = s;
  __syncthreads();
  if (ts == 0) {
    float M = mS[0][ci], S = sS[0][ci];
#pragma unroll
    for (int k = 1; k < 16; ++k) {
      float m2 = mS[k][ci], s2 = sS[k][ci];
      float nm = fmaxf(M, m2);
      S = S * __expf(M - nm) + s2 * __expf(m2 - nm);
      M = nm;
    }
    sS[0][ci] = M + logf(S);
  }
  __syncthreads();
  float lsd = sS[0][ci];
  for (int t = ts; t < T_SEQ; t += 16) {
    size_t i = ((size_t)b * T_SEQ + t) * 128 + c;
    out[i] -= lsd;
  }
}

// --------------------------------------------------------------------------------
extern "C" void kernel_launch(void* const* d_in, const int* in_sizes, int n_in,
                              void* d_out, int out_size, void* d_ws, size_t ws_size,
                              hipStream_t stream) {
  const int*   tokens = (const int*)d_in[0];
  const float* emb  = (const float*)d_in[1];
  const float* Wih0 = (const float*)d_in[2];
  const float* Whh0 = (const float*)d_in[3];
  const float* bih0 = (const float*)d_in[4];
  const float* bhh0 = (const float*)d_in[5];
  const float* Wih1 = (const float*)d_in[6];
  const float* Whh1 = (const float*)d_in[7];
  const float* bih1 = (const float*)d_in[8];
  const float* bhh1 = (const float*)d_in[9];
  const float* Wlin = (const float*)d_in[10];
  const float* blin = (const float*)d_in[11];
  float* out = (float*)d_out;

  uint8_t* ws = (uint8_t*)d_ws;
  size_t off = 0;
  auto alloc = [&](size_t bytes) -> void* {
    void* p = ws + off;
    off += (bytes + 255) & ~(size_t)255;
    return p;
  };
  u16* h1seq = (u16*)alloc((size_t)(T_SEQ + 1) * SLOT * 2);  // also holds x_bf pre-scan
  u16* h2seq = (u16*)alloc((size_t)(T_SEQ + 1) * SLOT * 2);
  u16* gxbuf = (u16*)alloc((size_t)16384 * NG * 2);          // packed gx[t][wg][g][b][ej]
  u16* wih0b = (u16*)alloc((size_t)NG * HDIM * 2);
  u16* whh0b = (u16*)alloc((size_t)NG * HDIM * 2);
  u16* wih1b = (u16*)alloc((size_t)NG * HDIM * 2);
  u16* whh1b = (u16*)alloc((size_t)NG * HDIM * 2);
  u16* wlinb = (u16*)alloc((size_t)128 * HDIM * 2);
  unsigned* flags = (unsigned*)alloc(65536);   // flags0 = 256 wave-flags, flags1 next

  cast5_kernel<<<dim3(12416), dim3(256), 0, stream>>>(
      Wih0, Whh0, Wih1, Whh1, Wlin, wih0b, whh0b, wih1b, whh1b, wlinb, flags);
  gather_cast_kernel<<<dim3(16384), dim3(256), 0, stream>>>(tokens, emb, h1seq);
  // gx0 = x @ W_ih0^T, written consumer-packed
  gemm_bt<2, false, false><<<dim3(128, 24), dim3(256), 0, stream>>>(
      h1seq, wih0b, gxbuf, nullptr, 16384, NG);
  // fused 2-layer scan (per-wave flags, 1 barrier/step, packed gx)
  fused_scan_kernel<<<dim3(128), dim3(256), 0, stream>>>(
      gxbuf, h1seq, h2seq, whh0b, wih1b, whh1b, bih0, bhh0, bih1, bhh1,
      flags, flags + 256 * FSTRIDE);
  // logits = h2 @ W_lin^T + b_lin -> d_out (fp32); A read from packed h2 slots
  gemm_bt<0, true, true><<<dim3(128, 1), dim3(256), 0, stream>>>(
      h2seq, wlinb, out, blin, 16384, 128);
  // log_softmax over T, in place
  logsoftmax_kernel<<<dim3(16, 8), dim3(256), 0, stream>>>(out);
}